// Round 3
// baseline (15772.011 us; speedup 1.0000x reference)
//
#include <hip/hip_runtime.h>
#include <stdint.h>

// Problem constants
#define BB 512
#define TT 82
#define DD 129
#define DXP 192      // x K padded to multiple of 64
#define HH 1024
#define G4 4096
#define NOUT 128
#define NSTEPS 100

typedef unsigned short u16;
typedef __attribute__((ext_vector_type(8))) _Float16 f16x8;
typedef __attribute__((ext_vector_type(8))) short short8;
typedef __attribute__((ext_vector_type(4))) float f32x4;

__device__ __forceinline__ u16 f2h(float f) {
  _Float16 h = (_Float16)f;   // v_cvt_f16_f32, RNE
  return __builtin_bit_cast(u16, h);
}
__device__ __forceinline__ float sigm(float x) { return 1.f / (1.f + __expf(-x)); }
__device__ __forceinline__ float tanhfast(float x) {
  float ax = fabsf(x);
  float e = __expf(2.f * ax);
  float t = 1.f - 2.f / (e + 1.f);
  return copysignf(t, x);
}
__device__ __forceinline__ void glds16(const void* g, void* l) {
  __builtin_amdgcn_global_load_lds((const __attribute__((address_space(1))) void*)g,
                                   (__attribute__((address_space(3))) void*)l, 16, 0, 0);
}

// Device-scope grid barrier (all 256 blocks co-resident by construction:
// 48 KB LDS -> max 3 blocks/CU, grid == #CUs). Monotonic counter, zeroed by
// a captured hipMemsetAsync before the persistent launch each call.
__device__ __forceinline__ void gridbar(unsigned* __restrict__ bar, unsigned target) {
  __syncthreads();
  if (threadIdx.x == 0) {
    __threadfence();   // agent release: L2 writeback so other XCDs see h/c
    __hip_atomic_fetch_add(bar, 1u, __ATOMIC_RELEASE, __HIP_MEMORY_SCOPE_AGENT);
    while (__hip_atomic_load(bar, __ATOMIC_RELAXED, __HIP_MEMORY_SCOPE_AGENT) < target)
      __builtin_amdgcn_s_sleep(2);
    __threadfence();   // agent acquire: invalidate stale L1/L2 lines
  }
  __syncthreads();
}

// One fused LSTM step GEMM (FUSE=1 semantics), K0 fixed = HH.
// G[M,4096] = A0[M,HH] @ W0^T + A1[M,K1] @ W1^T, cell epilogue.
// Tile: BM=64 (blockIdx.y), BN=128 (blockIdx.x), BK=64. 4 waves 2x2,
// wave tile 32x64. LDS XOR-swizzled; double-buffered prefetch.
__device__ __forceinline__ void rg(
    u16 (*At)[64 * 64], u16 (*Bt)[128 * 64],
    const u16* __restrict__ A0, const u16* __restrict__ W0,
    const u16* __restrict__ A1, int K1, const u16* __restrict__ W1,
    const float* __restrict__ bias, float* __restrict__ cst,
    u16* __restrict__ hnext, const int* __restrict__ lengths, int t)
{
  const int tid = threadIdx.x;
  const int lane = tid & 63;
  const int w = tid >> 6;
  const int waveM = w >> 1;
  const int waveN = w & 1;
  const int m0 = blockIdx.y * 64;
  const int n0 = blockIdx.x * 128;

  const int nIterT = 16 + (K1 >> 6);

  auto stage = [&](int i, int buf) {
    const u16* A; const u16* W; int K; int kb;
    if (i < 16) { A = A0; W = W0; K = HH; kb = i << 6; }
    else        { A = A1; W = W1; K = K1; kb = (i - 16) << 6; }
    #pragma unroll
    for (int j = 0; j < 2; ++j) {
      int slot = tid + j * 256;
      int r = slot >> 3, c = slot & 7;
      int g = c ^ (r & 7);
      glds16(A + (size_t)(m0 + r) * K + kb + g * 8,
             &At[buf][(j * 256 + w * 64) * 8]);
    }
    #pragma unroll
    for (int j = 0; j < 4; ++j) {
      int slot = tid + j * 256;
      int r = slot >> 3, c = slot & 7;
      int g = c ^ (r & 7);
      glds16(W + (size_t)(n0 + r) * K + kb + g * 8,
             &Bt[buf][(j * 256 + w * 64) * 8]);
    }
  };

  f32x4 acc[2][4] = {};

  stage(0, 0);
  for (int i = 0; i < nIterT; ++i) {
    __syncthreads();                       // drains stage(i); prefetch below
    if (i + 1 < nIterT) stage(i + 1, (i + 1) & 1);
    const int buf = i & 1;
    #pragma unroll
    for (int kc = 0; kc < 2; ++kc) {
      f16x8 af[2], bfr[4];
      const int gch = kc * 4 + (lane >> 4);
      #pragma unroll
      for (int ti = 0; ti < 2; ++ti) {
        int r = waveM * 32 + ti * 16 + (lane & 15);
        int c = gch ^ (r & 7);
        af[ti] = __builtin_bit_cast(f16x8, *(const short8*)&At[buf][(r * 8 + c) * 8]);
      }
      #pragma unroll
      for (int tj = 0; tj < 4; ++tj) {
        int r = waveN * 64 + tj * 16 + (lane & 15);
        int c = gch ^ (r & 7);
        bfr[tj] = __builtin_bit_cast(f16x8, *(const short8*)&Bt[buf][(r * 8 + c) * 8]);
      }
      #pragma unroll
      for (int ti = 0; ti < 2; ++ti)
        #pragma unroll
        for (int tj = 0; tj < 4; ++tj)
          acc[ti][tj] = __builtin_amdgcn_mfma_f32_16x16x32_f16(af[ti], bfr[tj], acc[ti][tj], 0, 0, 0);
    }
  }
  __syncthreads();

  const int col = lane & 15;
  const int rq = (lane >> 4) << 2;
  const int j = (blockIdx.x * 2 + waveN) * 16 + col;
  float bv[4];
  #pragma unroll
  for (int tj = 0; tj < 4; ++tj) bv[tj] = bias[n0 + waveN * 64 + tj * 16 + col];
  #pragma unroll
  for (int ti = 0; ti < 2; ++ti) {
    const int mb = m0 + waveM * 32 + ti * 16 + rq;
    #pragma unroll
    for (int r = 0; r < 4; ++r) {
      const int m = mb + r;
      const size_t idx = ((size_t)m << 10) + j;
      const bool upd = (t < 0) || (t < lengths[m]);
      if (upd) {
        float cv = cst[idx];
        float gi = acc[ti][0][r] + bv[0];
        float gf = acc[ti][1][r] + bv[1];
        float gg = acc[ti][2][r] + bv[2];
        float go = acc[ti][3][r] + bv[3];
        float cn = sigm(gf) * cv + sigm(gi) * tanhfast(gg);
        float hn = sigm(go) * tanhfast(cn);
        cst[idx] = cn;
        hnext[idx] = f2h(hn);
      } else {
        hnext[idx] = A0[idx];   // carry h through (c untouched)
      }
    }
  }
}

struct Ctx {
  const u16 *eWhh0b, *eWih0b, *eWhh1b, *eWih1b;
  const u16 *dWhh0b, *Weffb, *dWhh1b, *dWih1b;
  const float *be0, *be1, *beff0, *bd1;
  const u16 *xb;
  u16 *h0a, *h0b, *h1a, *h1b, *h1hist;
  float *c0, *c1;
};

// Persistent recurrence: encoder (pipelined l1(t) + l0(t+1) per phase) then
// decoder (dl0/dl1 alternating), grid barriers between dependent phases.
__global__ __launch_bounds__(256) void persist(Ctx c, const int* __restrict__ lengths,
                                               unsigned* __restrict__ bar)
{
  __shared__ __align__(16) u16 At[2][64 * 64];
  __shared__ __align__(16) u16 Bt[2][128 * 64];
  unsigned nb = 0;
  const int NJ = 1 + 2 * (TT - 1) + 1 + 2 * NSTEPS;   // 364 jobs
  for (int jj = 0; jj < NJ; ++jj) {
    const u16 *A0, *A1, *W0, *W1; const float *bias; float *cc;
    u16 *hn; int K1, t; bool dobar;
    if (jj == 0) {                       // l0(0)
      A0 = c.h0a; W0 = c.eWhh0b; A1 = c.xb; K1 = DXP; W1 = c.eWih0b;
      bias = c.be0; cc = c.c0; hn = c.h0b; t = 0; dobar = true;
    } else if (jj <= 2 * (TT - 1)) {     // pipelined pairs {l1(p), l0(p+1)}
      int p = (jj - 1) >> 1; bool sec = (jj - 1) & 1;
      if (!sec) {                        // l1(p)
        A0 = (p & 1) ? c.h1b : c.h1a; W0 = c.eWhh1b;
        A1 = ((p + 1) & 1) ? c.h0b : c.h0a; K1 = HH; W1 = c.eWih1b;
        bias = c.be1; cc = c.c1; hn = ((p + 1) & 1) ? c.h1b : c.h1a;
        t = p; dobar = false;
      } else {                           // l0(p+1)
        A0 = ((p + 1) & 1) ? c.h0b : c.h0a; W0 = c.eWhh0b;
        A1 = c.xb + (size_t)(p + 1) * BB * DXP; K1 = DXP; W1 = c.eWih0b;
        bias = c.be0; cc = c.c0; hn = (p & 1) ? c.h0b : c.h0a;
        t = p + 1; dobar = true;
      }
    } else if (jj == 2 * TT - 1) {       // final l1(TT-1) -> h1hist slice 0
      A0 = c.h1b; W0 = c.eWhh1b; A1 = c.h0a; K1 = HH; W1 = c.eWih1b;
      bias = c.be1; cc = c.c1; hn = c.h1hist; t = TT - 1; dobar = true;
    } else {                             // decoder
      int k = jj - 2 * TT; int s = k >> 1;
      const u16* hss = c.h1hist + (size_t)s * BB * HH;
      if (!(k & 1)) {                    // dl0(s)
        A0 = (s & 1) ? c.h0b : c.h0a; W0 = c.dWhh0b;
        A1 = hss; K1 = HH; W1 = c.Weffb;
        bias = c.beff0; cc = c.c0; hn = (s & 1) ? c.h0a : c.h0b;
        t = -1; dobar = true;
      } else {                           // dl1(s)
        A0 = hss; W0 = c.dWhh1b;
        A1 = (s & 1) ? c.h0a : c.h0b; K1 = HH; W1 = c.dWih1b;
        bias = c.bd1; cc = c.c1; hn = c.h1hist + (size_t)(s + 1) * BB * HH;
        t = -1; dobar = true;
      }
    }
    rg(At, Bt, A0, W0, A1, K1, W1, bias, cc, hn, lengths, t);
    if (dobar) gridbar(bar, (++nb) * 256u);
  }
}

// Parameter set for the standalone step GEMM (fallback + fc paths)
struct GemmP {
  const u16* A0; const u16* W0; const u16* A1; const u16* W1;
  const float* bias; float* cst; u16* hnext;
  int K0, K1, t;
};

// FUSE=1: LSTM cell epilogue. FUSE=0: per-step fc (N=128). FUSE=2: batched fc,
// row m = s*512+b -> out[(b*NSTEPS+s)*128+n]. gridDim.z==2: dual GEMM.
template <int FUSE>
__global__ __launch_bounds__(256) void step_gemm(
    GemmP q0, GemmP q1, const int* __restrict__ lengths, float* __restrict__ fout)
{
  const GemmP p = (blockIdx.z == 0) ? q0 : q1;
  __shared__ __align__(16) u16 At[2][64 * 64];
  __shared__ __align__(16) u16 Bt[2][128 * 64];
  const int tid = threadIdx.x;
  const int lane = tid & 63;
  const int w = tid >> 6;
  const int waveM = w >> 1;
  const int waveN = w & 1;
  const int m0 = blockIdx.y * 64;
  const int n0 = blockIdx.x * 128;

  const int nIter0 = p.K0 >> 6;
  const int nIterT = nIter0 + (p.K1 >> 6);

  auto stage = [&](int i, int buf) {
    const u16* A; const u16* W; int K; int kb;
    if (i < nIter0) { A = p.A0; W = p.W0; K = p.K0; kb = i << 6; }
    else            { A = p.A1; W = p.W1; K = p.K1; kb = (i - nIter0) << 6; }
    #pragma unroll
    for (int j = 0; j < 2; ++j) {
      int slot = tid + j * 256;
      int r = slot >> 3, c = slot & 7;
      int g = c ^ (r & 7);
      glds16(A + (size_t)(m0 + r) * K + kb + g * 8,
             &At[buf][(j * 256 + w * 64) * 8]);
    }
    #pragma unroll
    for (int j = 0; j < 4; ++j) {
      int slot = tid + j * 256;
      int r = slot >> 3, c = slot & 7;
      int g = c ^ (r & 7);
      glds16(W + (size_t)(n0 + r) * K + kb + g * 8,
             &Bt[buf][(j * 256 + w * 64) * 8]);
    }
  };

  f32x4 acc[2][4] = {};

  stage(0, 0);
  for (int i = 0; i < nIterT; ++i) {
    __syncthreads();
    if (i + 1 < nIterT) stage(i + 1, (i + 1) & 1);
    const int buf = i & 1;
    #pragma unroll
    for (int kc = 0; kc < 2; ++kc) {
      f16x8 af[2], bfr[4];
      const int gch = kc * 4 + (lane >> 4);
      #pragma unroll
      for (int ti = 0; ti < 2; ++ti) {
        int r = waveM * 32 + ti * 16 + (lane & 15);
        int c = gch ^ (r & 7);
        af[ti] = __builtin_bit_cast(f16x8, *(const short8*)&At[buf][(r * 8 + c) * 8]);
      }
      #pragma unroll
      for (int tj = 0; tj < 4; ++tj) {
        int r = waveN * 64 + tj * 16 + (lane & 15);
        int c = gch ^ (r & 7);
        bfr[tj] = __builtin_bit_cast(f16x8, *(const short8*)&Bt[buf][(r * 8 + c) * 8]);
      }
      #pragma unroll
      for (int ti = 0; ti < 2; ++ti)
        #pragma unroll
        for (int tj = 0; tj < 4; ++tj)
          acc[ti][tj] = __builtin_amdgcn_mfma_f32_16x16x32_f16(af[ti], bfr[tj], acc[ti][tj], 0, 0, 0);
    }
  }
  __syncthreads();

  const int col = lane & 15;
  const int rq = (lane >> 4) << 2;

  if (FUSE == 1) {
    const int j = (blockIdx.x * 2 + waveN) * 16 + col;
    float bv[4];
    #pragma unroll
    for (int tj = 0; tj < 4; ++tj) bv[tj] = p.bias[n0 + waveN * 64 + tj * 16 + col];
    #pragma unroll
    for (int ti = 0; ti < 2; ++ti) {
      const int mb = m0 + waveM * 32 + ti * 16 + rq;
      #pragma unroll
      for (int r = 0; r < 4; ++r) {
        const int m = mb + r;
        const size_t idx = ((size_t)m << 10) + j;
        const bool upd = (p.t < 0) || (p.t < lengths[m]);
        if (upd) {
          float cv = p.cst[idx];
          float gi = acc[ti][0][r] + bv[0];
          float gf = acc[ti][1][r] + bv[1];
          float gg = acc[ti][2][r] + bv[2];
          float go = acc[ti][3][r] + bv[3];
          float cn = sigm(gf) * cv + sigm(gi) * tanhfast(gg);
          float hn = sigm(go) * tanhfast(cn);
          p.cst[idx] = cn;
          p.hnext[idx] = f2h(hn);
        } else {
          p.hnext[idx] = p.A0[idx];
        }
      }
    }
  } else {
    #pragma unroll
    for (int ti = 0; ti < 2; ++ti) {
      const int mb = m0 + waveM * 32 + ti * 16 + rq;
      #pragma unroll
      for (int tj = 0; tj < 4; ++tj) {
        const int n = n0 + waveN * 64 + tj * 16 + col;
        const float bv = p.bias[n];
        #pragma unroll
        for (int r = 0; r < 4; ++r) {
          const int m = mb + r;
          const float v = acc[ti][tj][r] + bv;
          if (FUSE == 0) {
            fout[(size_t)m * (NSTEPS * NOUT) + n] = v;
          } else {
            fout[((size_t)(m & (BB - 1)) * NSTEPS + (m >> 9)) * NOUT + n] = v;
          }
        }
      }
    }
  }
}

// fp32 [R,C] -> fp16 [R,Cp], optional gate-row permutation (R=4096)
__global__ void conv_wp(const float* __restrict__ w, u16* __restrict__ wb,
                        int C, int Cp, int R, int perm, int total)
{
  int idx = blockIdx.x * 256 + threadIdx.x;
  if (idx >= total) return;
  int cc = idx % Cp;
  int n = idx / Cp;
  int orig = perm ? (((n >> 4) & 3) * (R >> 2) + (n >> 6) * 16 + (n & 15)) : n;
  wb[idx] = f2h(cc < C ? w[(size_t)orig * C + cc] : 0.f);
}

// permuted combined bias [4096]
__global__ void conv_b(const float* __restrict__ b1, const float* __restrict__ b2,
                       float* __restrict__ bp)
{
  int n = blockIdx.x * 256 + threadIdx.x;
  if (n >= G4) return;
  int orig = ((n >> 4) & 3) * HH + (n >> 6) * 16 + (n & 15);
  bp[n] = b1[orig] + b2[orig];
}

// Weff[n,k] = sum_j dWih0[orig(n), j] * fcW[j, k]   (fp32 math, fp16 permuted out)
__global__ void weff_kernel(const float* __restrict__ wih0, const float* __restrict__ fcW,
                            u16* __restrict__ weffb)
{
  int idx = blockIdx.x * 256 + threadIdx.x;    // n*1024 + k
  int k = idx & (HH - 1);
  int n = idx >> 10;
  int orig = ((n >> 4) & 3) * HH + (n >> 6) * 16 + (n & 15);
  float s = 0.f;
  #pragma unroll 4
  for (int j = 0; j < NOUT; ++j) s += wih0[orig * NOUT + j] * fcW[(size_t)j * HH + k];
  weffb[idx] = f2h(s);
}

// beff[n] = bih[orig] + bhh[orig] + sum_j dWih0[orig, j] * fcb[j]
__global__ void beff_kernel(const float* __restrict__ bih, const float* __restrict__ bhh,
                            const float* __restrict__ wih0, const float* __restrict__ fcb,
                            float* __restrict__ bp)
{
  int n = blockIdx.x * 256 + threadIdx.x;
  if (n >= G4) return;
  int orig = ((n >> 4) & 3) * HH + (n >> 6) * 16 + (n & 15);
  float s = bih[orig] + bhh[orig];
  #pragma unroll 4
  for (int j = 0; j < NOUT; ++j) s += wih0[orig * NOUT + j] * fcb[j];
  bp[n] = s;
}

// x [B,T,129] fp32 -> xb [T,B,192] fp16 zero-padded
__global__ void conv_x(const float* __restrict__ x, u16* __restrict__ xb)
{
  int idx = blockIdx.x * 256 + threadIdx.x;
  if (idx >= TT * BB * DXP) return;
  int k = idx % DXP;
  int tb = idx / DXP;
  int b = tb & (BB - 1);
  int t = tb / BB;
  xb[idx] = f2h(k < DD ? x[((size_t)b * TT + t) * DD + k] : 0.f);
}

extern "C" void kernel_launch(void* const* d_in, const int* in_sizes, int n_in,
                              void* d_out, int out_size, void* d_ws, size_t ws_size,
                              hipStream_t stream) {
  (void)in_sizes; (void)n_in; (void)out_size;
  const float* x     = (const float*)d_in[0];
  const int*   lens  = (const int*)d_in[1];
  const float* eWih0 = (const float*)d_in[2];
  const float* eWhh0 = (const float*)d_in[3];
  const float* ebih0 = (const float*)d_in[4];
  const float* ebhh0 = (const float*)d_in[5];
  const float* eWih1 = (const float*)d_in[6];
  const float* eWhh1 = (const float*)d_in[7];
  const float* ebih1 = (const float*)d_in[8];
  const float* ebhh1 = (const float*)d_in[9];
  const float* dWih0 = (const float*)d_in[10];
  const float* dWhh0 = (const float*)d_in[11];
  const float* dbih0 = (const float*)d_in[12];
  const float* dbhh0 = (const float*)d_in[13];
  const float* dWih1 = (const float*)d_in[14];
  const float* dWhh1 = (const float*)d_in[15];
  const float* dbih1 = (const float*)d_in[16];
  const float* dbhh1 = (const float*)d_in[17];
  const float* fcW   = (const float*)d_in[18];
  const float* fcb   = (const float*)d_in[19];
  float* out = (float*)d_out;

  char* p = (char*)d_ws;
  auto carve = [&](size_t bytes) -> void* {
    void* q = (void*)p;
    p += (bytes + 255) & ~(size_t)255;
    return q;
  };
  u16* eWih0b = (u16*)carve((size_t)G4 * DXP * 2);
  u16* eWhh0b = (u16*)carve((size_t)G4 * HH * 2);
  u16* eWih1b = (u16*)carve((size_t)G4 * HH * 2);
  u16* eWhh1b = (u16*)carve((size_t)G4 * HH * 2);
  u16* Weffb  = (u16*)carve((size_t)G4 * HH * 2);
  u16* dWhh0b = (u16*)carve((size_t)G4 * HH * 2);
  u16* dWih1b = (u16*)carve((size_t)G4 * HH * 2);
  u16* dWhh1b = (u16*)carve((size_t)G4 * HH * 2);
  u16* fcWb   = (u16*)carve((size_t)NOUT * HH * 2);
  float* be0  = (float*)carve((size_t)G4 * 4);
  float* be1  = (float*)carve((size_t)G4 * 4);
  float* beff0= (float*)carve((size_t)G4 * 4);
  float* bd1  = (float*)carve((size_t)G4 * 4);
  unsigned* bar = (unsigned*)carve(256);
  u16* xb     = (u16*)carve((size_t)TT * BB * DXP * 2);
  u16* h0p[2] = { (u16*)carve((size_t)BB * HH * 2), (u16*)carve((size_t)BB * HH * 2) };
  u16* h1p[2] = { (u16*)carve((size_t)BB * HH * 2), (u16*)carve((size_t)BB * HH * 2) };
  float* c0   = (float*)carve((size_t)BB * HH * 4);
  float* c1   = (float*)carve((size_t)BB * HH * 4);
  u16* h1hist = (u16*)carve((size_t)(NSTEPS + 1) * BB * HH * 2);  // carved LAST
  const size_t need = (size_t)(p - (char*)d_ws);
  const bool bigws = ws_size >= need;   // constant per run -> no capture branching

  auto cw = [&](const float* src, u16* dst, int C, int Cp, int R, int perm) {
    int total = R * Cp;
    conv_wp<<<dim3((total + 255) / 256), dim3(256), 0, stream>>>(src, dst, C, Cp, R, perm, total);
  };
  cw(eWih0, eWih0b, DD, DXP, G4, 1);
  cw(eWhh0, eWhh0b, HH, HH, G4, 1);
  cw(eWih1, eWih1b, HH, HH, G4, 1);
  cw(eWhh1, eWhh1b, HH, HH, G4, 1);
  cw(dWhh0, dWhh0b, HH, HH, G4, 1);
  cw(dWih1, dWih1b, HH, HH, G4, 1);
  cw(dWhh1, dWhh1b, HH, HH, G4, 1);
  cw(fcW, fcWb, HH, HH, NOUT, 0);
  weff_kernel<<<dim3(G4 * HH / 256), dim3(256), 0, stream>>>(dWih0, fcW, Weffb);
  conv_b<<<dim3(16), dim3(256), 0, stream>>>(ebih0, ebhh0, be0);
  conv_b<<<dim3(16), dim3(256), 0, stream>>>(ebih1, ebhh1, be1);
  beff_kernel<<<dim3(16), dim3(256), 0, stream>>>(dbih0, dbhh0, dWih0, fcb, beff0);
  conv_b<<<dim3(16), dim3(256), 0, stream>>>(dbih1, dbhh1, bd1);
  conv_x<<<dim3((TT * BB * DXP + 255) / 256), dim3(256), 0, stream>>>(x, xb);

  hipMemsetAsync(h0p[0], 0, (size_t)BB * HH * 2, stream);
  hipMemsetAsync(h1p[0], 0, (size_t)BB * HH * 2, stream);
  hipMemsetAsync(c0, 0, (size_t)BB * HH * 4, stream);
  hipMemsetAsync(c1, 0, (size_t)BB * HH * 4, stream);
  hipMemsetAsync(bar, 0, 4, stream);

  if (bigws) {
    Ctx c;
    c.eWhh0b = eWhh0b; c.eWih0b = eWih0b; c.eWhh1b = eWhh1b; c.eWih1b = eWih1b;
    c.dWhh0b = dWhh0b; c.Weffb = Weffb; c.dWhh1b = dWhh1b; c.dWih1b = dWih1b;
    c.be0 = be0; c.be1 = be1; c.beff0 = beff0; c.bd1 = bd1;
    c.xb = xb; c.h0a = h0p[0]; c.h0b = h0p[1]; c.h1a = h1p[0]; c.h1b = h1p[1];
    c.h1hist = h1hist; c.c0 = c0; c.c1 = c1;
    persist<<<dim3(32, 8, 1), 256, 0, stream>>>(c, lens, bar);
    // one batched fc over all steps: rows m = s*512 + b over h1hist slices 1..100
    GemmP pfc{ h1hist + (size_t)BB * HH, fcWb, nullptr, nullptr,
               fcb, nullptr, nullptr, HH, 0, -1 };
    step_gemm<2><<<dim3(1, (NSTEPS * BB) / 64, 1), 256, 0, stream>>>(pfc, pfc, nullptr, out);
  } else {
    const dim3 g1(32, 8, 1);
    const dim3 g2(32, 8, 2);
    auto L0 = [&](int t) -> GemmP {
      return GemmP{ h0p[t & 1], eWhh0b, xb + (size_t)t * BB * DXP, eWih0b,
                    be0, c0, h0p[(t + 1) & 1], HH, DXP, t };
    };
    auto L1e = [&](int t, u16* dst) -> GemmP {
      return GemmP{ h1p[t & 1], eWhh1b, h0p[(t + 1) & 1], eWih1b,
                    be1, c1, dst, HH, HH, t };
    };
    step_gemm<1><<<g1, 256, 0, stream>>>(L0(0), L0(0), lens, nullptr);
    for (int t = 0; t < TT - 1; ++t)
      step_gemm<1><<<g2, 256, 0, stream>>>(L1e(t, h1p[(t + 1) & 1]), L0(t + 1), lens, nullptr);
    step_gemm<1><<<g1, 256, 0, stream>>>(L1e(TT - 1, h1p[TT & 1]), L1e(TT - 1, h1p[TT & 1]), lens, nullptr);
    for (int s = 0; s < NSTEPS; ++s) {
      GemmP dl0{ h0p[s & 1], dWhh0b, h1p[s & 1], Weffb,
                 beff0, c0, h0p[(s + 1) & 1], HH, HH, -1 };
      step_gemm<1><<<g1, 256, 0, stream>>>(dl0, dl0, lens, nullptr);
      GemmP dl1{ h1p[s & 1], dWhh1b, h0p[(s + 1) & 1], dWih1b,
                 bd1, c1, h1p[(s + 1) & 1], HH, HH, -1 };
      step_gemm<1><<<g1, 256, 0, stream>>>(dl1, dl1, lens, nullptr);
      GemmP pfc{ h1p[(s + 1) & 1], fcWb, nullptr, nullptr, fcb, nullptr, nullptr, HH, 0, -1 };
      step_gemm<0><<<dim3(1, 8, 1), 256, 0, stream>>>(pfc, pfc, nullptr, out + (size_t)s * NOUT);
    }
  }
}

// Round 4
// 7853.245 us; speedup vs baseline: 2.0083x; 2.0083x over previous
//
#include <hip/hip_runtime.h>
#include <stdint.h>

// Problem constants
#define BB 512
#define TT 82
#define DD 129
#define DXP 192      // x K padded to multiple of 64
#define HH 1024
#define G4 4096
#define NOUT 128
#define NSTEPS 100

typedef unsigned short u16;
typedef __attribute__((ext_vector_type(8))) _Float16 f16x8;
typedef __attribute__((ext_vector_type(8))) short short8;
typedef __attribute__((ext_vector_type(4))) float f32x4;

__device__ __forceinline__ u16 f2h(float f) {
  _Float16 h = (_Float16)f;   // v_cvt_f16_f32, RNE
  return __builtin_bit_cast(u16, h);
}
__device__ __forceinline__ float sigm(float x) { return 1.f / (1.f + __expf(-x)); }
__device__ __forceinline__ float tanhfast(float x) {
  float ax = fabsf(x);
  float e = __expf(2.f * ax);
  float t = 1.f - 2.f / (e + 1.f);
  return copysignf(t, x);
}
__device__ __forceinline__ void glds16(const void* g, void* l) {
  __builtin_amdgcn_global_load_lds((const __attribute__((address_space(1))) void*)g,
                                   (__attribute__((address_space(3))) void*)l, 16, 0, 0);
}

// Parameter set for one fused step GEMM:
// G[M,N] = A0[M,K0] @ W0[N,K0]^T + A1[M,K1] @ W1[N,K1]^T   (K1 may be 0)
struct GemmP {
  const u16* A0; const u16* W0; const u16* A1; const u16* W1;
  const float* bias; float* cst; u16* hnext;
  int K0, K1, t;
};

// FUSE=1: N=4096 LSTM-cell epilogue (gate-permuted W rows; c fp32 in-place,
//         h fp16 -> hnext; mask t<lengths[m] freezes state, t<0 = always).
// FUSE=0: per-step fc, N=128; fout[m*12800 + n] = v  (fout = out + s*128)
// FUSE=2: batched fc over all decoder steps, M = NSTEPS*BB, row m = s*512+b;
//         out[(b*NSTEPS + s)*128 + n] = v
// gridDim.z==2 runs two independent GEMMs in one launch (blockIdx.z selects).
// Tile: BM=64 (blockIdx.y), BN=64 (blockIdx.x), BK=64. 256 thr = 4 waves 4x1,
// wave tile 16x64 (each wave owns a full 64-row gate group -> tj = gate).
// Grid = 512 blocks = 2 blocks/CU: one block's MFMA covers the other's staging
// latency (the R2 paired-encoder mechanism, now applied to every dispatch).
// LDS XOR-swizzled: slot(r,c16) holds global chunk c16^(r&7). Double-buffered.
template <int FUSE>
__global__ __launch_bounds__(256) void step_gemm(
    GemmP q0, GemmP q1, const int* __restrict__ lengths, float* __restrict__ fout)
{
  const GemmP p = (blockIdx.z == 0) ? q0 : q1;
  __shared__ __align__(16) u16 At[2][64 * 64];     // 16 KB
  __shared__ __align__(16) u16 Bt[2][64 * 64];     // 16 KB
  const int tid = threadIdx.x;
  const int lane = tid & 63;
  const int w = tid >> 6;          // waveM = w (4x1 wave layout)
  const int m0 = blockIdx.y * 64;
  const int n0 = blockIdx.x * 64;

  const int nIter0 = p.K0 >> 6;
  const int nIterT = nIter0 + (p.K1 >> 6);

  auto stage = [&](int i, int buf) {
    const u16* A; const u16* W; int K; int kb;
    if (i < nIter0) { A = p.A0; W = p.W0; K = p.K0; kb = i << 6; }
    else            { A = p.A1; W = p.W1; K = p.K1; kb = (i - nIter0) << 6; }
    // A: 64 rows x 8 chunks16 = 512 slots, 2/thread
    #pragma unroll
    for (int j = 0; j < 2; ++j) {
      int slot = tid + j * 256;
      int r = slot >> 3, c = slot & 7;
      int g = c ^ (r & 7);
      glds16(A + (size_t)(m0 + r) * K + kb + g * 8,
             &At[buf][(j * 256 + w * 64) * 8]);
    }
    // B: 64 rows x 8 chunks16 = 512 slots, 2/thread
    #pragma unroll
    for (int j = 0; j < 2; ++j) {
      int slot = tid + j * 256;
      int r = slot >> 3, c = slot & 7;
      int g = c ^ (r & 7);
      glds16(W + (size_t)(n0 + r) * K + kb + g * 8,
             &Bt[buf][(j * 256 + w * 64) * 8]);
    }
  };

  f32x4 acc[4] = {};

  stage(0, 0);
  for (int i = 0; i < nIterT; ++i) {
    __syncthreads();                       // drains stage(i); prefetch below
    if (i + 1 < nIterT) stage(i + 1, (i + 1) & 1);
    const int buf = i & 1;
    #pragma unroll
    for (int kc = 0; kc < 2; ++kc) {
      f16x8 af, bfr[4];
      const int gch = kc * 4 + (lane >> 4);
      {
        int r = w * 16 + (lane & 15);
        int c = gch ^ (r & 7);
        af = __builtin_bit_cast(f16x8, *(const short8*)&At[buf][(r * 8 + c) * 8]);
      }
      #pragma unroll
      for (int tj = 0; tj < 4; ++tj) {
        int r = tj * 16 + (lane & 15);
        int c = gch ^ (r & 7);
        bfr[tj] = __builtin_bit_cast(f16x8, *(const short8*)&Bt[buf][(r * 8 + c) * 8]);
      }
      #pragma unroll
      for (int tj = 0; tj < 4; ++tj)
        acc[tj] = __builtin_amdgcn_mfma_f32_16x16x32_f16(af, bfr[tj], acc[tj], 0, 0, 0);
    }
  }
  __syncthreads();

  const int col = lane & 15;
  const int rq = (lane >> 4) << 2;

  if (FUSE == 1) {
    // block covers one 64-row gate group: unit j, gates = tj
    const int j = blockIdx.x * 16 + col;
    float bv[4];
    #pragma unroll
    for (int tj = 0; tj < 4; ++tj) bv[tj] = p.bias[n0 + tj * 16 + col];
    const int mb = m0 + w * 16 + rq;
    #pragma unroll
    for (int r = 0; r < 4; ++r) {
      const int m = mb + r;
      const size_t idx = ((size_t)m << 10) + j;
      const bool upd = (p.t < 0) || (p.t < lengths[m]);
      if (upd) {
        float cv = p.cst[idx];
        float gi = acc[0][r] + bv[0];
        float gf = acc[1][r] + bv[1];
        float gg = acc[2][r] + bv[2];
        float go = acc[3][r] + bv[3];
        float cn = sigm(gf) * cv + sigm(gi) * tanhfast(gg);
        float hn = sigm(go) * tanhfast(cn);
        p.cst[idx] = cn;
        p.hnext[idx] = f2h(hn);
      } else {
        p.hnext[idx] = p.A0[idx];   // carry h through (c untouched)
      }
    }
  } else {
    const int mb = m0 + w * 16 + rq;
    #pragma unroll
    for (int tj = 0; tj < 4; ++tj) {
      const int n = n0 + tj * 16 + col;
      const float bv = p.bias[n];
      #pragma unroll
      for (int r = 0; r < 4; ++r) {
        const int m = mb + r;
        const float v = acc[tj][r] + bv;
        if (FUSE == 0) {
          fout[(size_t)m * (NSTEPS * NOUT) + n] = v;
        } else {
          // m = s*512 + b  ->  out[(b*NSTEPS + s)*128 + n]
          fout[((size_t)(m & (BB - 1)) * NSTEPS + (m >> 9)) * NOUT + n] = v;
        }
      }
    }
  }
}

// fp32 [R,C] -> fp16 [R,Cp], optional gate-row permutation (R=4096)
__global__ void conv_wp(const float* __restrict__ w, u16* __restrict__ wb,
                        int C, int Cp, int R, int perm, int total)
{
  int idx = blockIdx.x * 256 + threadIdx.x;
  if (idx >= total) return;
  int cc = idx % Cp;
  int n = idx / Cp;
  int orig = perm ? (((n >> 4) & 3) * (R >> 2) + (n >> 6) * 16 + (n & 15)) : n;
  wb[idx] = f2h(cc < C ? w[(size_t)orig * C + cc] : 0.f);
}

// permuted combined bias [4096]
__global__ void conv_b(const float* __restrict__ b1, const float* __restrict__ b2,
                       float* __restrict__ bp)
{
  int n = blockIdx.x * 256 + threadIdx.x;
  if (n >= G4) return;
  int orig = ((n >> 4) & 3) * HH + (n >> 6) * 16 + (n & 15);
  bp[n] = b1[orig] + b2[orig];
}

// Weff[n,k] = sum_j dWih0[orig(n), j] * fcW[j, k]   (fp32 math, fp16 permuted out)
__global__ void weff_kernel(const float* __restrict__ wih0, const float* __restrict__ fcW,
                            u16* __restrict__ weffb)
{
  int idx = blockIdx.x * 256 + threadIdx.x;    // n*1024 + k
  int k = idx & (HH - 1);
  int n = idx >> 10;
  int orig = ((n >> 4) & 3) * HH + (n >> 6) * 16 + (n & 15);
  float s = 0.f;
  #pragma unroll 4
  for (int j = 0; j < NOUT; ++j) s += wih0[orig * NOUT + j] * fcW[(size_t)j * HH + k];
  weffb[idx] = f2h(s);
}

// beff[n] = bih[orig] + bhh[orig] + sum_j dWih0[orig, j] * fcb[j]
__global__ void beff_kernel(const float* __restrict__ bih, const float* __restrict__ bhh,
                            const float* __restrict__ wih0, const float* __restrict__ fcb,
                            float* __restrict__ bp)
{
  int n = blockIdx.x * 256 + threadIdx.x;
  if (n >= G4) return;
  int orig = ((n >> 4) & 3) * HH + (n >> 6) * 16 + (n & 15);
  float s = bih[orig] + bhh[orig];
  #pragma unroll 4
  for (int j = 0; j < NOUT; ++j) s += wih0[orig * NOUT + j] * fcb[j];
  bp[n] = s;
}

// x [B,T,129] fp32 -> xb [T,B,192] fp16 zero-padded
__global__ void conv_x(const float* __restrict__ x, u16* __restrict__ xb)
{
  int idx = blockIdx.x * 256 + threadIdx.x;
  if (idx >= TT * BB * DXP) return;
  int k = idx % DXP;
  int tb = idx / DXP;
  int b = tb & (BB - 1);
  int t = tb / BB;
  xb[idx] = f2h(k < DD ? x[((size_t)b * TT + t) * DD + k] : 0.f);
}

extern "C" void kernel_launch(void* const* d_in, const int* in_sizes, int n_in,
                              void* d_out, int out_size, void* d_ws, size_t ws_size,
                              hipStream_t stream) {
  (void)in_sizes; (void)n_in; (void)out_size;
  const float* x     = (const float*)d_in[0];
  const int*   lens  = (const int*)d_in[1];
  const float* eWih0 = (const float*)d_in[2];
  const float* eWhh0 = (const float*)d_in[3];
  const float* ebih0 = (const float*)d_in[4];
  const float* ebhh0 = (const float*)d_in[5];
  const float* eWih1 = (const float*)d_in[6];
  const float* eWhh1 = (const float*)d_in[7];
  const float* ebih1 = (const float*)d_in[8];
  const float* ebhh1 = (const float*)d_in[9];
  const float* dWih0 = (const float*)d_in[10];
  const float* dWhh0 = (const float*)d_in[11];
  const float* dbih0 = (const float*)d_in[12];
  const float* dbhh0 = (const float*)d_in[13];
  const float* dWih1 = (const float*)d_in[14];
  const float* dWhh1 = (const float*)d_in[15];
  const float* dbih1 = (const float*)d_in[16];
  const float* dbhh1 = (const float*)d_in[17];
  const float* fcW   = (const float*)d_in[18];
  const float* fcb   = (const float*)d_in[19];
  float* out = (float*)d_out;

  char* p = (char*)d_ws;
  auto carve = [&](size_t bytes) -> void* {
    void* q = (void*)p;
    p += (bytes + 255) & ~(size_t)255;
    return q;
  };
  u16* eWih0b = (u16*)carve((size_t)G4 * DXP * 2);
  u16* eWhh0b = (u16*)carve((size_t)G4 * HH * 2);
  u16* eWih1b = (u16*)carve((size_t)G4 * HH * 2);
  u16* eWhh1b = (u16*)carve((size_t)G4 * HH * 2);
  u16* Weffb  = (u16*)carve((size_t)G4 * HH * 2);
  u16* dWhh0b = (u16*)carve((size_t)G4 * HH * 2);
  u16* dWih1b = (u16*)carve((size_t)G4 * HH * 2);
  u16* dWhh1b = (u16*)carve((size_t)G4 * HH * 2);
  u16* fcWb   = (u16*)carve((size_t)NOUT * HH * 2);
  float* be0  = (float*)carve((size_t)G4 * 4);
  float* be1  = (float*)carve((size_t)G4 * 4);
  float* beff0= (float*)carve((size_t)G4 * 4);
  float* bd1  = (float*)carve((size_t)G4 * 4);
  u16* xb     = (u16*)carve((size_t)TT * BB * DXP * 2);
  u16* h0p[2] = { (u16*)carve((size_t)BB * HH * 2), (u16*)carve((size_t)BB * HH * 2) };
  u16* h1p[2] = { (u16*)carve((size_t)BB * HH * 2), (u16*)carve((size_t)BB * HH * 2) };
  float* c0   = (float*)carve((size_t)BB * HH * 4);
  float* c1   = (float*)carve((size_t)BB * HH * 4);
  u16* h1hist = (u16*)carve((size_t)(NSTEPS + 1) * BB * HH * 2);  // carved LAST
  const size_t need = (size_t)(p - (char*)d_ws);
  const bool bigws = ws_size >= need;   // constant per run -> no capture branching

  auto cw = [&](const float* src, u16* dst, int C, int Cp, int R, int perm) {
    int total = R * Cp;
    conv_wp<<<dim3((total + 255) / 256), dim3(256), 0, stream>>>(src, dst, C, Cp, R, perm, total);
  };
  cw(eWih0, eWih0b, DD, DXP, G4, 1);
  cw(eWhh0, eWhh0b, HH, HH, G4, 1);
  cw(eWih1, eWih1b, HH, HH, G4, 1);
  cw(eWhh1, eWhh1b, HH, HH, G4, 1);
  cw(dWhh0, dWhh0b, HH, HH, G4, 1);
  cw(dWih1, dWih1b, HH, HH, G4, 1);
  cw(dWhh1, dWhh1b, HH, HH, G4, 1);
  cw(fcW, fcWb, HH, HH, NOUT, 0);
  weff_kernel<<<dim3(G4 * HH / 256), dim3(256), 0, stream>>>(dWih0, fcW, Weffb);
  conv_b<<<dim3(16), dim3(256), 0, stream>>>(ebih0, ebhh0, be0);
  conv_b<<<dim3(16), dim3(256), 0, stream>>>(ebih1, ebhh1, be1);
  beff_kernel<<<dim3(16), dim3(256), 0, stream>>>(dbih0, dbhh0, dWih0, fcb, beff0);
  conv_b<<<dim3(16), dim3(256), 0, stream>>>(dbih1, dbhh1, bd1);
  conv_x<<<dim3((TT * BB * DXP + 255) / 256), dim3(256), 0, stream>>>(x, xb);

  hipMemsetAsync(h0p[0], 0, (size_t)BB * HH * 2, stream);
  hipMemsetAsync(h1p[0], 0, (size_t)BB * HH * 2, stream);
  hipMemsetAsync(c0, 0, (size_t)BB * HH * 4, stream);
  hipMemsetAsync(c1, 0, (size_t)BB * HH * 4, stream);

  const dim3 g1(64, 8, 1);     // 512 blocks = 2 blocks/CU
  const dim3 g2(64, 8, 2);     // encoder pair: 1024 blocks = 4 blocks/CU

  // encoder layer-0 step t: reads h0p[t&1], writes h0p[(t+1)&1]
  auto L0 = [&](int t) -> GemmP {
    return GemmP{ h0p[t & 1], eWhh0b, xb + (size_t)t * BB * DXP, eWih0b,
                  be0, c0, h0p[(t + 1) & 1], HH, DXP, t };
  };
  // encoder layer-1 step t: reads h1p[t&1] and h0p[(t+1)&1], writes dst
  auto L1e = [&](int t, u16* dst) -> GemmP {
    return GemmP{ h1p[t & 1], eWhh1b, h0p[(t + 1) & 1], eWih1b,
                  be1, c1, dst, HH, HH, t };
  };

  // prologue + software-pipelined encoder: K(t) = { l1(t) , l0(t+1) }
  step_gemm<1><<<g1, 256, 0, stream>>>(L0(0), L0(0), lens, nullptr);
  for (int t = 0; t < TT - 1; ++t)
    step_gemm<1><<<g2, 256, 0, stream>>>(L1e(t, h1p[(t + 1) & 1]), L0(t + 1), lens, nullptr);
  u16* h1final = bigws ? h1hist : h1p[TT & 1];      // TT even -> h1p[0]
  step_gemm<1><<<g1, 256, 0, stream>>>(L1e(TT - 1, h1final), L1e(TT - 1, h1final), lens, nullptr);

  if (bigws) {
    // decoder with fc folded into layer0 (Weff = dWih0 @ fcW); h1 kept as history
    auto hs = [&](int s) { return h1hist + (size_t)s * BB * HH; };
    for (int s = 0; s < NSTEPS; ++s) {
      GemmP dl0{ h0p[s & 1], dWhh0b, hs(s), Weffb,
                 beff0, c0, h0p[(s + 1) & 1], HH, HH, -1 };
      step_gemm<1><<<g1, 256, 0, stream>>>(dl0, dl0, lens, nullptr);
      GemmP dl1{ hs(s), dWhh1b, h0p[(s + 1) & 1], dWih1b,
                 bd1, c1, hs(s + 1), HH, HH, -1 };
      step_gemm<1><<<g1, 256, 0, stream>>>(dl1, dl1, lens, nullptr);
    }
    // one batched fc over all steps: rows m = s*512 + b over h1hist slices 1..100
    GemmP pfc{ hs(1), fcWb, nullptr, nullptr, fcb, nullptr, nullptr, HH, 0, -1 };
    step_gemm<2><<<dim3(2, (NSTEPS * BB) / 64, 1), 256, 0, stream>>>(pfc, pfc, nullptr, out);
  } else {
    // fallback: h1 double-buffer + per-step fc (still fc-folded l0, no outb dep)
    for (int s = 0; s < NSTEPS; ++s) {
      GemmP dl0{ h0p[s & 1], dWhh0b, h1p[s & 1], Weffb,
                 beff0, c0, h0p[(s + 1) & 1], HH, HH, -1 };
      step_gemm<1><<<g1, 256, 0, stream>>>(dl0, dl0, lens, nullptr);
      GemmP dl1{ h1p[s & 1], dWhh1b, h0p[(s + 1) & 1], dWih1b,
                 bd1, c1, h1p[(s + 1) & 1], HH, HH, -1 };
      step_gemm<1><<<g1, 256, 0, stream>>>(dl1, dl1, lens, nullptr);
      GemmP pfc{ h1p[(s + 1) & 1], fcWb, nullptr, nullptr, fcb, nullptr, nullptr, HH, 0, -1 };
      step_gemm<0><<<dim3(2, 8, 1), 256, 0, stream>>>(pfc, pfc, nullptr, out + (size_t)s * NOUT);
    }
  }
}

// Round 5
// 6440.823 us; speedup vs baseline: 2.4488x; 1.2193x over previous
//
#include <hip/hip_runtime.h>
#include <stdint.h>

// Problem constants
#define BB 512
#define TT 82
#define DD 129
#define DXP 192      // x K padded to multiple of 64
#define HH 1024
#define G4 4096
#define NOUT 128
#define NSTEPS 100

typedef unsigned short u16;
typedef __attribute__((ext_vector_type(8))) _Float16 f16x8;
typedef __attribute__((ext_vector_type(8))) short short8;
typedef __attribute__((ext_vector_type(4))) float f32x4;

__device__ __forceinline__ u16 f2h(float f) {
  _Float16 h = (_Float16)f;   // v_cvt_f16_f32, RNE
  return __builtin_bit_cast(u16, h);
}
__device__ __forceinline__ float sigm(float x) { return 1.f / (1.f + __expf(-x)); }
__device__ __forceinline__ float tanhfast(float x) {
  float ax = fabsf(x);
  float e = __expf(2.f * ax);
  float t = 1.f - 2.f / (e + 1.f);
  return copysignf(t, x);
}
__device__ __forceinline__ void glds16(const void* g, void* l) {
  __builtin_amdgcn_global_load_lds((const __attribute__((address_space(1))) void*)g,
                                   (__attribute__((address_space(3))) void*)l, 16, 0, 0);
}

// Parameter set for one fused step GEMM:
// G[M,N] = A0[M,K0] @ W0[N,K0]^T + A1[M,K1] @ W1[N,K1]^T   (K1 may be 0)
// mode (FUSE=1 only): 0 = cell epilogue; 1 = cell epilogue + scratch add;
//                     2 = raw partial -> scratch (f32, no bias/cell)
struct GemmP {
  const u16* A0; const u16* W0; const u16* A1; const u16* W1;
  const float* bias; float* cst; u16* hnext;
  int K0, K1, t;
  float* scratch; int mode;
};

// FUSE=1: N=4096 LSTM family (gate-permuted W rows; see mode above; mask
//         t<lengths[m] freezes state, t<0 = always update).
// FUSE=0: per-step fc, N=128; fout[m*12800 + n] = v
// FUSE=2: batched fc, M = NSTEPS*BB, row m = s*512+b -> out[(b*NSTEPS+s)*128+n]
// gridDim.z==2 runs two independent GEMMs in one launch (blockIdx.z selects).
// Tile: BM=64 (blockIdx.y), BN=64 (blockIdx.x), BK=64. 256 thr = 4 waves 4x1,
// wave tile 16x64 (each wave covers a full 64-row gate group -> tj = gate).
// Decoder pairs run 1024 blocks = 4 blocks/CU; per-XCD L2 footprint:
// 1MB A (shared by both z) + 2x1MB B slices = 3MB < 4MB L2.
// LDS XOR-swizzled: slot(r,c16) holds global chunk c16^(r&7). Double-buffered.
template <int FUSE>
__global__ __launch_bounds__(256) void step_gemm(
    GemmP q0, GemmP q1, const int* __restrict__ lengths, float* __restrict__ fout)
{
  const GemmP p = (blockIdx.z == 0) ? q0 : q1;
  __shared__ __align__(16) u16 At[2][64 * 64];     // 16 KB
  __shared__ __align__(16) u16 Bt[2][64 * 64];     // 16 KB
  const int tid = threadIdx.x;
  const int lane = tid & 63;
  const int w = tid >> 6;          // waveM = w (4x1 wave layout)
  const int m0 = blockIdx.y * 64;
  const int n0 = blockIdx.x * 64;

  const int nIter0 = p.K0 >> 6;
  const int nIterT = nIter0 + (p.K1 >> 6);

  auto stage = [&](int i, int buf) {
    const u16* A; const u16* W; int K; int kb;
    if (i < nIter0) { A = p.A0; W = p.W0; K = p.K0; kb = i << 6; }
    else            { A = p.A1; W = p.W1; K = p.K1; kb = (i - nIter0) << 6; }
    // A: 64 rows x 8 chunks16 = 512 slots, 2/thread
    #pragma unroll
    for (int j = 0; j < 2; ++j) {
      int slot = tid + j * 256;
      int r = slot >> 3, c = slot & 7;
      int g = c ^ (r & 7);
      glds16(A + (size_t)(m0 + r) * K + kb + g * 8,
             &At[buf][(j * 256 + w * 64) * 8]);
    }
    // B: 64 rows x 8 chunks16 = 512 slots, 2/thread
    #pragma unroll
    for (int j = 0; j < 2; ++j) {
      int slot = tid + j * 256;
      int r = slot >> 3, c = slot & 7;
      int g = c ^ (r & 7);
      glds16(W + (size_t)(n0 + r) * K + kb + g * 8,
             &Bt[buf][(j * 256 + w * 64) * 8]);
    }
  };

  f32x4 acc[4] = {};

  stage(0, 0);
  for (int i = 0; i < nIterT; ++i) {
    __syncthreads();                       // drains stage(i); prefetch below
    if (i + 1 < nIterT) stage(i + 1, (i + 1) & 1);
    const int buf = i & 1;
    #pragma unroll
    for (int kc = 0; kc < 2; ++kc) {
      f16x8 af, bfr[4];
      const int gch = kc * 4 + (lane >> 4);
      {
        int r = w * 16 + (lane & 15);
        int c = gch ^ (r & 7);
        af = __builtin_bit_cast(f16x8, *(const short8*)&At[buf][(r * 8 + c) * 8]);
      }
      #pragma unroll
      for (int tj = 0; tj < 4; ++tj) {
        int r = tj * 16 + (lane & 15);
        int c = gch ^ (r & 7);
        bfr[tj] = __builtin_bit_cast(f16x8, *(const short8*)&Bt[buf][(r * 8 + c) * 8]);
      }
      #pragma unroll
      for (int tj = 0; tj < 4; ++tj)
        acc[tj] = __builtin_amdgcn_mfma_f32_16x16x32_f16(af, bfr[tj], acc[tj], 0, 0, 0);
    }
  }
  __syncthreads();

  const int col = lane & 15;
  const int rq = (lane >> 4) << 2;

  if (FUSE == 1) {
    const int mb = m0 + w * 16 + rq;
    if (p.mode == 2) {
      // raw partial gates -> scratch (f32, exact)
      #pragma unroll
      for (int tj = 0; tj < 4; ++tj) {
        const int n = n0 + tj * 16 + col;
        #pragma unroll
        for (int r = 0; r < 4; ++r)
          p.scratch[((size_t)(mb + r) << 12) + n] = acc[tj][r];
      }
    } else {
      // block covers one 64-row gate group: unit j, gates = tj
      const int j = blockIdx.x * 16 + col;
      float bv[4];
      #pragma unroll
      for (int tj = 0; tj < 4; ++tj) bv[tj] = p.bias[n0 + tj * 16 + col];
      #pragma unroll
      for (int r = 0; r < 4; ++r) {
        const int m = mb + r;
        const size_t idx = ((size_t)m << 10) + j;
        const bool upd = (p.t < 0) || (p.t < lengths[m]);
        if (upd) {
          float g[4];
          #pragma unroll
          for (int tj = 0; tj < 4; ++tj) g[tj] = acc[tj][r] + bv[tj];
          if (p.mode == 1) {
            #pragma unroll
            for (int tj = 0; tj < 4; ++tj)
              g[tj] += p.scratch[((size_t)m << 12) + n0 + tj * 16 + col];
          }
          float cv = p.cst[idx];
          float cn = sigm(g[1]) * cv + sigm(g[0]) * tanhfast(g[2]);
          float hn = sigm(g[3]) * tanhfast(cn);
          p.cst[idx] = cn;
          p.hnext[idx] = f2h(hn);
        } else {
          p.hnext[idx] = p.A0[idx];   // carry h through (c untouched)
        }
      }
    }
  } else {
    const int mb = m0 + w * 16 + rq;
    #pragma unroll
    for (int tj = 0; tj < 4; ++tj) {
      const int n = n0 + tj * 16 + col;
      const float bv = p.bias[n];
      #pragma unroll
      for (int r = 0; r < 4; ++r) {
        const int m = mb + r;
        const float v = acc[tj][r] + bv;
        if (FUSE == 0) {
          fout[(size_t)m * (NSTEPS * NOUT) + n] = v;
        } else {
          // m = s*512 + b  ->  out[(b*NSTEPS + s)*128 + n]
          fout[((size_t)(m & (BB - 1)) * NSTEPS + (m >> 9)) * NOUT + n] = v;
        }
      }
    }
  }
}

// fp32 [R,C] -> fp16 [R,Cp], optional gate-row permutation (R=4096)
__global__ void conv_wp(const float* __restrict__ w, u16* __restrict__ wb,
                        int C, int Cp, int R, int perm, int total)
{
  int idx = blockIdx.x * 256 + threadIdx.x;
  if (idx >= total) return;
  int cc = idx % Cp;
  int n = idx / Cp;
  int orig = perm ? (((n >> 4) & 3) * (R >> 2) + (n >> 6) * 16 + (n & 15)) : n;
  wb[idx] = f2h(cc < C ? w[(size_t)orig * C + cc] : 0.f);
}

// permuted combined bias [4096]
__global__ void conv_b(const float* __restrict__ b1, const float* __restrict__ b2,
                       float* __restrict__ bp)
{
  int n = blockIdx.x * 256 + threadIdx.x;
  if (n >= G4) return;
  int orig = ((n >> 4) & 3) * HH + (n >> 6) * 16 + (n & 15);
  bp[n] = b1[orig] + b2[orig];
}

// Weff[n,k] = sum_j dWih0[orig(n), j] * fcW[j, k]   (fp32 math, fp16 permuted out)
__global__ void weff_kernel(const float* __restrict__ wih0, const float* __restrict__ fcW,
                            u16* __restrict__ weffb)
{
  int idx = blockIdx.x * 256 + threadIdx.x;    // n*1024 + k
  int k = idx & (HH - 1);
  int n = idx >> 10;
  int orig = ((n >> 4) & 3) * HH + (n >> 6) * 16 + (n & 15);
  float s = 0.f;
  #pragma unroll 4
  for (int j = 0; j < NOUT; ++j) s += wih0[orig * NOUT + j] * fcW[(size_t)j * HH + k];
  weffb[idx] = f2h(s);
}

// beff[n] = bih[orig] + bhh[orig] + sum_j dWih0[orig, j] * fcb[j]
__global__ void beff_kernel(const float* __restrict__ bih, const float* __restrict__ bhh,
                            const float* __restrict__ wih0, const float* __restrict__ fcb,
                            float* __restrict__ bp)
{
  int n = blockIdx.x * 256 + threadIdx.x;
  if (n >= G4) return;
  int orig = ((n >> 4) & 3) * HH + (n >> 6) * 16 + (n & 15);
  float s = bih[orig] + bhh[orig];
  #pragma unroll 4
  for (int j = 0; j < NOUT; ++j) s += wih0[orig * NOUT + j] * fcb[j];
  bp[n] = s;
}

// x [B,T,129] fp32 -> xb [T,B,192] fp16 zero-padded
__global__ void conv_x(const float* __restrict__ x, u16* __restrict__ xb)
{
  int idx = blockIdx.x * 256 + threadIdx.x;
  if (idx >= TT * BB * DXP) return;
  int k = idx % DXP;
  int tb = idx / DXP;
  int b = tb & (BB - 1);
  int t = tb / BB;
  xb[idx] = f2h(k < DD ? x[((size_t)b * TT + t) * DD + k] : 0.f);
}

extern "C" void kernel_launch(void* const* d_in, const int* in_sizes, int n_in,
                              void* d_out, int out_size, void* d_ws, size_t ws_size,
                              hipStream_t stream) {
  (void)in_sizes; (void)n_in; (void)out_size;
  const float* x     = (const float*)d_in[0];
  const int*   lens  = (const int*)d_in[1];
  const float* eWih0 = (const float*)d_in[2];
  const float* eWhh0 = (const float*)d_in[3];
  const float* ebih0 = (const float*)d_in[4];
  const float* ebhh0 = (const float*)d_in[5];
  const float* eWih1 = (const float*)d_in[6];
  const float* eWhh1 = (const float*)d_in[7];
  const float* ebih1 = (const float*)d_in[8];
  const float* ebhh1 = (const float*)d_in[9];
  const float* dWih0 = (const float*)d_in[10];
  const float* dWhh0 = (const float*)d_in[11];
  const float* dbih0 = (const float*)d_in[12];
  const float* dbhh0 = (const float*)d_in[13];
  const float* dWih1 = (const float*)d_in[14];
  const float* dWhh1 = (const float*)d_in[15];
  const float* dbih1 = (const float*)d_in[16];
  const float* dbhh1 = (const float*)d_in[17];
  const float* fcW   = (const float*)d_in[18];
  const float* fcb   = (const float*)d_in[19];
  float* out = (float*)d_out;

  char* p = (char*)d_ws;
  auto carve = [&](size_t bytes) -> void* {
    void* q = (void*)p;
    p += (bytes + 255) & ~(size_t)255;
    return q;
  };
  u16* eWih0b = (u16*)carve((size_t)G4 * DXP * 2);
  u16* eWhh0b = (u16*)carve((size_t)G4 * HH * 2);
  u16* eWih1b = (u16*)carve((size_t)G4 * HH * 2);
  u16* eWhh1b = (u16*)carve((size_t)G4 * HH * 2);
  u16* Weffb  = (u16*)carve((size_t)G4 * HH * 2);
  u16* dWhh0b = (u16*)carve((size_t)G4 * HH * 2);
  u16* dWih1b = (u16*)carve((size_t)G4 * HH * 2);
  u16* dWhh1b = (u16*)carve((size_t)G4 * HH * 2);
  u16* fcWb   = (u16*)carve((size_t)NOUT * HH * 2);
  float* be0  = (float*)carve((size_t)G4 * 4);
  float* be1  = (float*)carve((size_t)G4 * 4);
  float* beff0= (float*)carve((size_t)G4 * 4);
  float* bd1  = (float*)carve((size_t)G4 * 4);
  u16* xb     = (u16*)carve((size_t)TT * BB * DXP * 2);
  u16* h0p[2] = { (u16*)carve((size_t)BB * HH * 2), (u16*)carve((size_t)BB * HH * 2) };
  u16* h1p[2] = { (u16*)carve((size_t)BB * HH * 2), (u16*)carve((size_t)BB * HH * 2) };
  float* c0   = (float*)carve((size_t)BB * HH * 4);
  float* c1   = (float*)carve((size_t)BB * HH * 4);
  float* scr0 = (float*)carve((size_t)BB * G4 * 4);   // 8 MB partial gates l0
  float* scr1 = (float*)carve((size_t)BB * G4 * 4);   // 8 MB partial gates l1
  u16* h1hist = (u16*)carve((size_t)(NSTEPS + 1) * BB * HH * 2);  // carved LAST
  const size_t need = (size_t)(p - (char*)d_ws);
  const bool bigws = ws_size >= need;   // constant per run -> no capture branching

  auto cw = [&](const float* src, u16* dst, int C, int Cp, int R, int perm) {
    int total = R * Cp;
    conv_wp<<<dim3((total + 255) / 256), dim3(256), 0, stream>>>(src, dst, C, Cp, R, perm, total);
  };
  cw(eWih0, eWih0b, DD, DXP, G4, 1);
  cw(eWhh0, eWhh0b, HH, HH, G4, 1);
  cw(eWih1, eWih1b, HH, HH, G4, 1);
  cw(eWhh1, eWhh1b, HH, HH, G4, 1);
  cw(dWhh0, dWhh0b, HH, HH, G4, 1);
  cw(dWih1, dWih1b, HH, HH, G4, 1);
  cw(dWhh1, dWhh1b, HH, HH, G4, 1);
  cw(fcW, fcWb, HH, HH, NOUT, 0);
  weff_kernel<<<dim3(G4 * HH / 256), dim3(256), 0, stream>>>(dWih0, fcW, Weffb);
  conv_b<<<dim3(16), dim3(256), 0, stream>>>(ebih0, ebhh0, be0);
  conv_b<<<dim3(16), dim3(256), 0, stream>>>(ebih1, ebhh1, be1);
  beff_kernel<<<dim3(16), dim3(256), 0, stream>>>(dbih0, dbhh0, dWih0, fcb, beff0);
  conv_b<<<dim3(16), dim3(256), 0, stream>>>(dbih1, dbhh1, bd1);
  conv_x<<<dim3((TT * BB * DXP + 255) / 256), dim3(256), 0, stream>>>(x, xb);

  hipMemsetAsync(h0p[0], 0, (size_t)BB * HH * 2, stream);
  hipMemsetAsync(h1p[0], 0, (size_t)BB * HH * 2, stream);
  hipMemsetAsync(c0, 0, (size_t)BB * HH * 4, stream);
  hipMemsetAsync(c1, 0, (size_t)BB * HH * 4, stream);

  const dim3 g1(64, 8, 1);     // 512 blocks = 2 blocks/CU
  const dim3 g2(64, 8, 2);     // pair: 1024 blocks = 4 blocks/CU

  // encoder layer-0 step t: reads h0p[t&1], writes h0p[(t+1)&1]
  auto L0 = [&](int t) -> GemmP {
    return GemmP{ h0p[t & 1], eWhh0b, xb + (size_t)t * BB * DXP, eWih0b,
                  be0, c0, h0p[(t + 1) & 1], HH, DXP, t, nullptr, 0 };
  };
  // encoder layer-1 step t: reads h1p[t&1] and h0p[(t+1)&1], writes dst
  auto L1e = [&](int t, u16* dst) -> GemmP {
    return GemmP{ h1p[t & 1], eWhh1b, h0p[(t + 1) & 1], eWih1b,
                  be1, c1, dst, HH, HH, t, nullptr, 0 };
  };

  // prologue + software-pipelined encoder: K(t) = { l1(t) , l0(t+1) }
  step_gemm<1><<<g1, 256, 0, stream>>>(L0(0), L0(0), lens, nullptr);
  for (int t = 0; t < TT - 1; ++t)
    step_gemm<1><<<g2, 256, 0, stream>>>(L1e(t, h1p[(t + 1) & 1]), L0(t + 1), lens, nullptr);

  if (bigws) {
    auto hs = [&](int s) { return h1hist + (size_t)s * BB * HH; };
    // final encoder l1 paired with decoder dl0a(0) = Whh0 . h0_final -> scr0
    // (both depend only on L0(81), which wrote h0p[0])
    GemmP pa00{ h0p[0], dWhh0b, nullptr, nullptr, nullptr, nullptr, nullptr,
                HH, 0, -1, scr0, 2 };
    step_gemm<1><<<g2, 256, 0, stream>>>(L1e(TT - 1, hs(0)), pa00, lens, nullptr);

    // decoder: 2 phases per step, each a pair of K=1024 half-GEMMs.
    // P1(s): dl0b = Weff.h1(s) + scr0 -> cell -> h0(s+1)   || dl1a = Whh1.h1(s) -> scr1
    // P2(s): dl1b = Wih1.h0(s+1) + scr1 -> cell -> h1(s+1) || dl0a(s+1) = Whh0.h0(s+1) -> scr0
    for (int s = 0; s < NSTEPS; ++s) {
      GemmP d0b{ hs(s), Weffb, nullptr, nullptr, beff0, c0, h0p[(s + 1) & 1],
                 HH, 0, -1, scr0, 1 };
      GemmP d1a{ hs(s), dWhh1b, nullptr, nullptr, nullptr, nullptr, nullptr,
                 HH, 0, -1, scr1, 2 };
      step_gemm<1><<<g2, 256, 0, stream>>>(d0b, d1a, lens, nullptr);

      GemmP d1b{ h0p[(s + 1) & 1], dWih1b, nullptr, nullptr, bd1, c1, hs(s + 1),
                 HH, 0, -1, scr1, 1 };
      if (s + 1 < NSTEPS) {
        GemmP d0a{ h0p[(s + 1) & 1], dWhh0b, nullptr, nullptr, nullptr, nullptr, nullptr,
                   HH, 0, -1, scr0, 2 };
        step_gemm<1><<<g2, 256, 0, stream>>>(d1b, d0a, lens, nullptr);
      } else {
        step_gemm<1><<<g1, 256, 0, stream>>>(d1b, d1b, lens, nullptr);
      }
    }
    // one batched fc over all steps: rows m = s*512 + b over h1hist slices 1..100
    GemmP pfc{ hs(1), fcWb, nullptr, nullptr, fcb, nullptr, nullptr, HH, 0, -1,
               nullptr, 0 };
    step_gemm<2><<<dim3(2, (NSTEPS * BB) / 64, 1), 256, 0, stream>>>(pfc, pfc, nullptr, out);
  } else {
    // fallback: no scratch split; h1 double-buffer + per-step fc (fc-folded l0)
    step_gemm<1><<<g1, 256, 0, stream>>>(L1e(TT - 1, h1p[TT & 1]),
                                         L1e(TT - 1, h1p[TT & 1]), lens, nullptr);
    for (int s = 0; s < NSTEPS; ++s) {
      GemmP dl0{ h0p[s & 1], dWhh0b, h1p[s & 1], Weffb,
                 beff0, c0, h0p[(s + 1) & 1], HH, HH, -1, nullptr, 0 };
      step_gemm<1><<<g1, 256, 0, stream>>>(dl0, dl0, lens, nullptr);
      GemmP dl1{ h1p[s & 1], dWhh1b, h0p[(s + 1) & 1], dWih1b,
                 bd1, c1, h1p[(s + 1) & 1], HH, HH, -1, nullptr, 0 };
      step_gemm<1><<<g1, 256, 0, stream>>>(dl1, dl1, lens, nullptr);
      GemmP pfc{ h1p[(s + 1) & 1], fcWb, nullptr, nullptr, fcb, nullptr, nullptr,
                 HH, 0, -1, nullptr, 0 };
      step_gemm<0><<<dim3(2, 8, 1), 256, 0, stream>>>(pfc, pfc, nullptr, out + (size_t)s * NOUT);
    }
  }
}